// Round 1
// baseline (141.058 us; speedup 1.0000x reference)
//
#include <hip/hip_runtime.h>

#define EPSF 1e-10f

struct alignas(8) Node { int par; float c; };

__device__ __forceinline__ float signed_log(float x) {
    float sg = (x > 0.f) ? 1.f : ((x < 0.f) ? -1.f : 0.f);
    return logf(fabsf(x) + EPSF) * sg;
}

// ---- Stage 1: per-CC sigmoid scores -----------------------------------------
__global__ void scores_kernel(const float* __restrict__ attrs,
                              const float* __restrict__ weight,
                              const float* __restrict__ bias,
                              float* __restrict__ scores, int num_cc) {
    int i = blockIdx.x * blockDim.x + threadIdx.x;
    if (i >= num_cc) return;
    const float* f = attrs + (long long)i * 15;
    float w[17];
#pragma unroll
    for (int k = 0; k < 17; ++k) w[k] = weight[k];
    float acc = bias[0];
    acc += w[0] * f[0] + w[1] * f[1] + w[2] * f[2] + w[3] * f[3];
    acc += w[4] * logf(f[4]);                      // log(area)
#pragma unroll
    for (int j = 0; j < 9; ++j) acc += w[5 + j] * signed_log(f[6 + j]);
    float lshape = sqrtf(f[7]) / (sqrtf(f[6]) + EPSF);
    acc += w[14] * lshape;
    acc += w[15] * cosf(f[5]);
    acc += w[16] * sinf(f[5]);
    scores[i] = 1.f / (1.f + expf(-acc));
}

// ---- Stage 2: per-pixel contribution, packed with parent --------------------
__global__ void pack_kernel(const float* __restrict__ diff,
                            const int* __restrict__ parent,
                            const int* __restrict__ cc_id,
                            const float* __restrict__ scores,
                            Node* __restrict__ packed, int n) {
    int i = blockIdx.x * blockDim.x + threadIdx.x;
    if (i >= n) return;
    Node nd;
    nd.par = parent[i];
    nd.c = diff[i] * scores[cc_id[i]];
    packed[i] = nd;
}

__global__ void contrib_kernel(const float* __restrict__ diff,
                               const int* __restrict__ cc_id,
                               const float* __restrict__ scores,
                               float* __restrict__ contrib, int n) {
    int i = blockIdx.x * blockDim.x + threadIdx.x;
    if (i >= n) return;
    contrib[i] = diff[i] * scores[cc_id[i]];
}

// ---- Stage 3: range-staged chain walk (parent[i] < i) -----------------------
// Base range [0, range_end): full walk to root (parent of root == -1).
__global__ void walk_base(const Node* __restrict__ packed,
                          float* __restrict__ out, int range_end) {
    int i = blockIdx.x * blockDim.x + threadIdx.x;
    if (i >= range_end) return;
    float s = 0.f;
    int cur = i;
    while (cur >= 0) {
        Node nd = packed[cur];
        s += nd.c;
        cur = nd.par;
    }
    out[i] = s;
}

// Phase range [lo, hi): walk until chain drops below lo, then add finished out.
__global__ void walk_phase(const Node* __restrict__ packed,
                           float* __restrict__ out, int lo, int hi) {
    int i = lo + blockIdx.x * blockDim.x + threadIdx.x;
    if (i >= hi) return;
    float s = 0.f;
    int cur = i;
    while (cur >= lo) {
        Node nd = packed[cur];
        s += nd.c;
        cur = nd.par;
    }
    s += out[cur];   // cur in [0, lo): already final (stream-ordered kernels)
    out[i] = s;
}

// Unpacked fallbacks (used only if ws too small for the packed array).
__global__ void walk_base2(const int* __restrict__ parent,
                           const float* __restrict__ contrib,
                           float* __restrict__ out, int range_end) {
    int i = blockIdx.x * blockDim.x + threadIdx.x;
    if (i >= range_end) return;
    float s = 0.f;
    int cur = i;
    while (cur >= 0) {
        s += contrib[cur];
        cur = parent[cur];
    }
    out[i] = s;
}

__global__ void walk_phase2(const int* __restrict__ parent,
                            const float* __restrict__ contrib,
                            float* __restrict__ out, int lo, int hi) {
    int i = lo + blockIdx.x * blockDim.x + threadIdx.x;
    if (i >= hi) return;
    float s = 0.f;
    int cur = i;
    while (cur >= lo) {
        s += contrib[cur];
        cur = parent[cur];
    }
    s += out[cur];
    out[i] = s;
}

static inline int iminh(int a, int b) { return a < b ? a : b; }

extern "C" void kernel_launch(void* const* d_in, const int* in_sizes, int n_in,
                              void* d_out, int out_size, void* d_ws, size_t ws_size,
                              hipStream_t stream) {
    const float* diff   = (const float*)d_in[0];
    const float* attrs  = (const float*)d_in[1];
    const float* weight = (const float*)d_in[2];
    const float* bias   = (const float*)d_in[3];
    const int*   parent = (const int*)d_in[4];
    const int*   cc_id  = (const int*)d_in[5];
    float* out = (float*)d_out;

    const int n      = in_sizes[0];        // 2048*2048
    const int num_cc = in_sizes[1] / 15;   // 1<<20

    float* scores = (float*)d_ws;
    const size_t scores_bytes = (size_t)num_cc * sizeof(float);
    const size_t packed_need  = scores_bytes + (size_t)n * sizeof(Node);
    const bool use_packed = ws_size >= packed_need;

    const int TB = 256;
    scores_kernel<<<(num_cc + TB - 1) / TB, TB, 0, stream>>>(attrs, weight, bias, scores, num_cc);

    const int B = 65536;                   // base range; ratio-4 phases after
    if (use_packed) {
        Node* packed = (Node*)((char*)d_ws + scores_bytes);
        pack_kernel<<<(n + TB - 1) / TB, TB, 0, stream>>>(diff, parent, cc_id, scores, packed, n);
        int base_end = iminh(B, n);
        walk_base<<<(base_end + TB - 1) / TB, TB, 0, stream>>>(packed, out, base_end);
        int lo = base_end;
        while (lo < n) {
            long long hi_ll = (long long)lo * 4;
            int hi = (hi_ll > n) ? n : (int)hi_ll;
            walk_phase<<<((hi - lo) + TB - 1) / TB, TB, 0, stream>>>(packed, out, lo, hi);
            lo = hi;
        }
    } else {
        float* contrib = (float*)((char*)d_ws + scores_bytes);
        contrib_kernel<<<(n + TB - 1) / TB, TB, 0, stream>>>(diff, cc_id, scores, contrib, n);
        int base_end = iminh(B, n);
        walk_base2<<<(base_end + TB - 1) / TB, TB, 0, stream>>>(parent, contrib, out, base_end);
        int lo = base_end;
        while (lo < n) {
            long long hi_ll = (long long)lo * 4;
            int hi = (hi_ll > n) ? n : (int)hi_ll;
            walk_phase2<<<((hi - lo) + TB - 1) / TB, TB, 0, stream>>>(parent, contrib, out, lo, hi);
            lo = hi;
        }
    }
}

// Round 2
// 130.542 us; speedup vs baseline: 1.0806x; 1.0806x over previous
//
#include <hip/hip_runtime.h>

#define EPSF 1e-10f

struct alignas(8) Node { int par; float c; };

typedef int   v4i __attribute__((ext_vector_type(4)));
typedef float v4f __attribute__((ext_vector_type(4)));

__device__ __forceinline__ float signed_log(float x) {
    float sg = (x > 0.f) ? 1.f : ((x < 0.f) ? -1.f : 0.f);
    return logf(fabsf(x) + EPSF) * sg;
}

// ---- Stage 1: per-CC sigmoid scores -----------------------------------------
__global__ void scores_kernel(const float* __restrict__ attrs,
                              const float* __restrict__ weight,
                              const float* __restrict__ bias,
                              float* __restrict__ scores, int num_cc) {
    int i = blockIdx.x * blockDim.x + threadIdx.x;
    if (i >= num_cc) return;
    const float* f = attrs + (long long)i * 15;
    float w[17];
#pragma unroll
    for (int k = 0; k < 17; ++k) w[k] = weight[k];
    float acc = bias[0];
    acc += w[0] * f[0] + w[1] * f[1] + w[2] * f[2] + w[3] * f[3];
    acc += w[4] * logf(f[4]);                      // log(area)
#pragma unroll
    for (int j = 0; j < 9; ++j) acc += w[5 + j] * signed_log(f[6 + j]);
    float lshape = sqrtf(f[7]) / (sqrtf(f[6]) + EPSF);
    acc += w[14] * lshape;
    acc += w[15] * cosf(f[5]);
    acc += w[16] * sinf(f[5]);
    __builtin_nontemporal_store(1.f / (1.f + expf(-acc)), &scores[i]);
}

// ---- Stage 2: per-pixel contribution packed with parent (4 px / thread) -----
__global__ void pack_kernel4(const v4f* __restrict__ diff4,
                             const v4i* __restrict__ parent4,
                             const v4i* __restrict__ cc4,
                             const float* __restrict__ scores,
                             v4i* __restrict__ packed2, int n4) {
    int i = blockIdx.x * blockDim.x + threadIdx.x;
    if (i >= n4) return;
    v4f d = __builtin_nontemporal_load(&diff4[i]);
    v4i p = __builtin_nontemporal_load(&parent4[i]);
    v4i c = __builtin_nontemporal_load(&cc4[i]);
    float s0 = scores[c.x], s1 = scores[c.y], s2 = scores[c.z], s3 = scores[c.w];
    v4i o0, o1;
    o0.x = p.x; o0.y = __float_as_int(d.x * s0);
    o0.z = p.y; o0.w = __float_as_int(d.y * s1);
    o1.x = p.z; o1.y = __float_as_int(d.z * s2);
    o1.z = p.w; o1.w = __float_as_int(d.w * s3);
    __builtin_nontemporal_store(o0, &packed2[2 * i]);
    __builtin_nontemporal_store(o1, &packed2[2 * i + 1]);
}

__global__ void pack_kernel(const float* __restrict__ diff,
                            const int* __restrict__ parent,
                            const int* __restrict__ cc_id,
                            const float* __restrict__ scores,
                            Node* __restrict__ packed, int lo, int n) {
    int i = lo + blockIdx.x * blockDim.x + threadIdx.x;
    if (i >= n) return;
    Node nd;
    nd.par = parent[i];
    nd.c = diff[i] * scores[cc_id[i]];
    packed[i] = nd;
}

// ---- Stage 3: range-staged chain walk (parent[i] < i) -----------------------
__device__ __forceinline__ void load_self_nt(const Node* p, int i, int& par, float& c) {
    long long raw = __builtin_nontemporal_load((const long long*)(p + i));
    par = (int)(raw & 0xffffffffLL);
    c = __int_as_float((int)(raw >> 32));
}

// Base range [0, range_end): full walk to root (parent of root == -1).
__global__ void walk_base(const Node* __restrict__ packed,
                          float* __restrict__ out, int range_end) {
    int i = blockIdx.x * blockDim.x + threadIdx.x;
    if (i >= range_end) return;
    int cur; float s;
    load_self_nt(packed, i, cur, s);
    while (cur >= 0) {
        Node nd = packed[cur];     // cached: region is small & hot
        s += nd.c;
        cur = nd.par;
    }
    __builtin_nontemporal_store(s, &out[i]);
}

// Phase range [lo, hi): walk until chain drops below lo, then add finished out.
__global__ void walk_phase(const Node* __restrict__ packed,
                           float* __restrict__ out, int lo, int hi) {
    int i = lo + blockIdx.x * blockDim.x + threadIdx.x;
    if (i >= hi) return;
    int cur; float s;
    load_self_nt(packed, i, cur, s);   // streaming: keep out of L2
    while (cur >= lo) {
        Node nd = packed[cur];         // cached: random within phase region
        s += nd.c;
        cur = nd.par;
    }
    s += out[cur];                     // cached: random in finished [0, lo)
    __builtin_nontemporal_store(s, &out[i]);
}

// Unpacked fallbacks (only if ws too small for the packed array).
__global__ void walk_base2(const int* __restrict__ parent,
                           const float* __restrict__ contrib,
                           float* __restrict__ out, int range_end) {
    int i = blockIdx.x * blockDim.x + threadIdx.x;
    if (i >= range_end) return;
    float s = 0.f;
    int cur = i;
    while (cur >= 0) { s += contrib[cur]; cur = parent[cur]; }
    out[i] = s;
}

__global__ void walk_phase2(const int* __restrict__ parent,
                            const float* __restrict__ contrib,
                            float* __restrict__ out, int lo, int hi) {
    int i = lo + blockIdx.x * blockDim.x + threadIdx.x;
    if (i >= hi) return;
    float s = 0.f;
    int cur = i;
    while (cur >= lo) { s += contrib[cur]; cur = parent[cur]; }
    s += out[cur];
    out[i] = s;
}

__global__ void contrib_kernel(const float* __restrict__ diff,
                               const int* __restrict__ cc_id,
                               const float* __restrict__ scores,
                               float* __restrict__ contrib, int n) {
    int i = blockIdx.x * blockDim.x + threadIdx.x;
    if (i >= n) return;
    contrib[i] = diff[i] * scores[cc_id[i]];
}

static inline int iminh(int a, int b) { return a < b ? a : b; }

extern "C" void kernel_launch(void* const* d_in, const int* in_sizes, int n_in,
                              void* d_out, int out_size, void* d_ws, size_t ws_size,
                              hipStream_t stream) {
    const float* diff   = (const float*)d_in[0];
    const float* attrs  = (const float*)d_in[1];
    const float* weight = (const float*)d_in[2];
    const float* bias   = (const float*)d_in[3];
    const int*   parent = (const int*)d_in[4];
    const int*   cc_id  = (const int*)d_in[5];
    float* out = (float*)d_out;

    const int n      = in_sizes[0];        // 2048*2048
    const int num_cc = in_sizes[1] / 15;   // 1<<20

    float* scores = (float*)d_ws;
    const size_t scores_bytes = (size_t)num_cc * sizeof(float);
    const size_t packed_need  = scores_bytes + (size_t)n * sizeof(Node);
    const bool use_packed = ws_size >= packed_need;

    const int TB = 256;
    scores_kernel<<<(num_cc + TB - 1) / TB, TB, 0, stream>>>(attrs, weight, bias, scores, num_cc);

    const int BASE   = 131072;             // [0, BASE): full walk (L2-resident)
    const int R2_MIN = 1 << 19;            // ranges >= 512K use ratio 2; below use ratio 4

    if (use_packed) {
        Node* packed = (Node*)((char*)d_ws + scores_bytes);
        if ((n & 3) == 0) {
            pack_kernel4<<<(n / 4 + TB - 1) / TB, TB, 0, stream>>>(
                (const v4f*)diff, (const v4i*)parent, (const v4i*)cc_id, scores, (v4i*)packed, n / 4);
        } else {
            pack_kernel<<<(n + TB - 1) / TB, TB, 0, stream>>>(diff, parent, cc_id, scores, packed, 0, n);
        }
        int base_end = iminh(BASE, n);
        walk_base<<<(base_end + TB - 1) / TB, TB, 0, stream>>>(packed, out, base_end);
        int lo = base_end;
        while (lo < n) {
            int ratio = (lo < R2_MIN) ? 4 : 2;
            long long hi_ll = (long long)lo * ratio;
            int hi = (hi_ll > n) ? n : (int)hi_ll;
            walk_phase<<<((hi - lo) + TB - 1) / TB, TB, 0, stream>>>(packed, out, lo, hi);
            lo = hi;
        }
    } else {
        float* contrib = (float*)((char*)d_ws + scores_bytes);
        contrib_kernel<<<(n + TB - 1) / TB, TB, 0, stream>>>(diff, cc_id, scores, contrib, n);
        int base_end = iminh(BASE, n);
        walk_base2<<<(base_end + TB - 1) / TB, TB, 0, stream>>>(parent, contrib, out, base_end);
        int lo = base_end;
        while (lo < n) {
            int ratio = (lo < R2_MIN) ? 4 : 2;
            long long hi_ll = (long long)lo * ratio;
            int hi = (hi_ll > n) ? n : (int)hi_ll;
            walk_phase2<<<((hi - lo) + TB - 1) / TB, TB, 0, stream>>>(parent, contrib, out, lo, hi);
            lo = hi;
        }
    }
}